// Round 5
// baseline (219.104 us; speedup 1.0000x reference)
//
#include <hip/hip_runtime.h>

#define T_LEN 2048
#define BT_DIM 8192  // B*T

typedef __attribute__((ext_vector_type(8))) short s16x8;
typedef __attribute__((ext_vector_type(4))) float f32x4;

typedef __attribute__((address_space(1))) void gvoid_t;
typedef __attribute__((address_space(3))) void svoid_t;

__device__ __forceinline__ unsigned short f2bf(float f) {
  unsigned int u = __builtin_bit_cast(unsigned int, f);
  u += 0x7fffu + ((u >> 16) & 1u);
  return (unsigned short)(u >> 16);
}
__device__ __forceinline__ float bf2f(unsigned short u) {
  unsigned int v = (unsigned int)u << 16;
  return __builtin_bit_cast(float, v);
}
__device__ __forceinline__ void gload16(const void* g, void* l) {
  __builtin_amdgcn_global_load_lds((gvoid_t*)g, (svoid_t*)l, 16, 0, 0);
}

// ---------------------------------------------------------------------------
// GEMM core: C[m,n] = sum_k A[m,k]*B[n,k], 128x128 tile, BK=64, 4 waves,
// 2-phase double-buffered LDS. T2 swizzle: LDS dest linear (gload_lds
// requirement), per-lane GLOBAL source col pre-swizzled, ds_read col XOR'd
// with the same involution (byte ^= (row&7)<<4) -> 16-way conflict becomes
// 2-way (free).
// EPI: 2 = bf16 out, local-row window [rlo,rhi)
//      3 = f32 out + obias[col]
//      4 = bf16 out + per-16-row chunk column sums into `sums` (mainP)
// ---------------------------------------------------------------------------
template<int EPI>
__device__ __forceinline__ void gemm_body(
    const unsigned short* __restrict__ A, const unsigned short* __restrict__ B,
    void* __restrict__ Cv, int lda, int ldb, int ldc, int K, int m0, int n0,
    const float* __restrict__ obias, float* __restrict__ sums, int ygrp,
    int rlo, int rhi)
{
  __shared__ unsigned short As[2 * 128 * 64];   // 2 x 16KB
  __shared__ unsigned short Bs[2 * 128 * 64];
  const int tid  = threadIdx.x;
  const int wave = tid >> 6;
  const int lane = tid & 63;
  const int wr = wave >> 1, wc = wave & 1;
  const int trow = tid >> 3;                              // 0..31
  const int scol = (((tid & 7) ^ ((tid >> 3) & 7)) << 3); // swizzled k-col

  const unsigned short* Ap = A + (size_t)(m0 + trow) * lda + scol;
  const unsigned short* Bp = B + (size_t)(n0 + trow) * ldb + scol;

  f32x4 acc[4][4] = {};

  auto stage = [&](int buf, int kt) {
    char* ab = (char*)As + buf * 16384 + wave * 1024;
    char* bb = (char*)Bs + buf * 16384 + wave * 1024;
#pragma unroll
    for (int it = 0; it < 4; ++it) {
      gload16(Ap + (size_t)it * 32 * lda + kt, ab + it * 4096);
      gload16(Bp + (size_t)it * 32 * ldb + kt, bb + it * 4096);
    }
  };

  stage(0, 0);
  __syncthreads();
  int cur = 0;
  const int xr = (lane & 7) << 3;   // read-side XOR (elements)
  for (int kt = 64; kt <= K; kt += 64) {
    if (kt < K) stage(cur ^ 1, kt);     // prefetch next tile (overlaps MFMA)
#pragma unroll
    for (int ks = 0; ks < 2; ++ks) {
      const int kk = ((ks << 5) + ((lane >> 4) << 3)) ^ xr;
      const int ra = (wr << 6) + (lane & 15);
      const int rb = (wc << 6) + (lane & 15);
      s16x8 af[4], bfr[4];
#pragma unroll
      for (int i = 0; i < 4; ++i)
        af[i] = *(const s16x8*)&As[cur * 8192 + (ra + (i << 4)) * 64 + kk];
#pragma unroll
      for (int i = 0; i < 4; ++i)
        bfr[i] = *(const s16x8*)&Bs[cur * 8192 + (rb + (i << 4)) * 64 + kk];
#pragma unroll
      for (int i = 0; i < 4; ++i)
#pragma unroll
        for (int j = 0; j < 4; ++j)
          acc[i][j] = __builtin_amdgcn_mfma_f32_16x16x32_bf16(af[i], bfr[j], acc[i][j], 0, 0, 0);
    }
    __syncthreads();                    // drains vmcnt -> next buffer ready
    cur ^= 1;
  }

  // Epilogue. C/D layout (m89-verified): col = lane&15, row = (lane>>4)*4 + reg
  if (EPI == 2) {
    unsigned short* C = (unsigned short*)Cv;
#pragma unroll
    for (int i = 0; i < 4; ++i) {
      const int lr0 = (wr << 6) + (i << 4) + ((lane >> 4) << 2);
#pragma unroll
      for (int j = 0; j < 4; ++j) {
        const int c = n0 + (wc << 6) + (j << 4) + (lane & 15);
#pragma unroll
        for (int rr = 0; rr < 4; ++rr) {
          const int lr = lr0 + rr;
          if (lr >= rlo && lr < rhi)
            C[(size_t)(m0 + lr) * ldc + c] = f2bf(acc[i][j][rr]);
        }
      }
    }
  } else if (EPI == 3) {
    float* C = (float*)Cv;
    float ob[4];
#pragma unroll
    for (int j = 0; j < 4; ++j)
      ob[j] = obias[n0 + (wc << 6) + (j << 4) + (lane & 15)];
#pragma unroll
    for (int i = 0; i < 4; ++i) {
      const int r0 = m0 + (wr << 6) + (i << 4) + ((lane >> 4) << 2);
#pragma unroll
      for (int j = 0; j < 4; ++j) {
        const int c = n0 + (wc << 6) + (j << 4) + (lane & 15);
#pragma unroll
        for (int rr = 0; rr < 4; ++rr)
          C[(size_t)(r0 + rr) * ldc + c] = acc[i][j][rr] + ob[j];
      }
    }
  } else {  // EPI == 4: bf16 out (n0==0) + per-16-row-chunk column sums
    unsigned short* C = (unsigned short*)Cv;
#pragma unroll
    for (int i = 0; i < 4; ++i) {
      const int r0 = m0 + (wr << 6) + (i << 4) + ((lane >> 4) << 2);
#pragma unroll
      for (int j = 0; j < 4; ++j) {
        const int c = (wc << 6) + (j << 4) + (lane & 15);
#pragma unroll
        for (int rr = 0; rr < 4; ++rr)
          C[(size_t)(r0 + rr) * ldc + c] = f2bf(acc[i][j][rr]);
      }
    }
    // streams: y=1: wc0->s2(off0), wc1->s6(off64); y=2 wc0->s3(off128); y=3 wc0->sZ(off192)
    int soff = -1;
    if (ygrp == 1) soff = wc << 6;
    else if (ygrp == 2 && wc == 0) soff = 128;
    else if (ygrp == 3 && wc == 0) soff = 192;
    if (soff >= 0) {
#pragma unroll
      for (int i = 0; i < 4; ++i) {     // each i = one 16-row chunk
        const int R0 = m0 + (wr << 6) + (i << 4);
        const int b_ = R0 >> 11, ch = (R0 & 2047) >> 4;
#pragma unroll
        for (int j = 0; j < 4; ++j) {
          float v = acc[i][j][0] + acc[i][j][1] + acc[i][j][2] + acc[i][j][3];
          v += __shfl_xor(v, 16);
          v += __shfl_xor(v, 32);
          if (lane < 16)
            sums[(((b_ << 7) + ch) << 8) + soff + (j << 4) + lane] = v;
        }
      }
    }
  }
}

// ---------------------------------------------------------------------------
// Weight folds
// ---------------------------------------------------------------------------
__global__ __launch_bounds__(256) void smallA_k(
    const unsigned short* BQ, const unsigned short* BK, const unsigned short* BI,
    const unsigned short* WOb, const unsigned short* WQt, const unsigned short* WKt,
    const unsigned short* Winvt, const unsigned short* UcatT,
    unsigned short* Gcat, unsigned short* Hb, unsigned short* Gfin)
{
  const int bx = blockIdx.x;
  const unsigned short *A, *B; unsigned short* C; int ldc, m0, n0;
  switch (blockIdx.y) {
    case 0:  A = BQ;  B = WQt;   C = Gcat;              ldc = 1024; m0 = 0; n0 = bx * 128; break;
    case 1:  A = BK;  B = WKt;   C = Gcat + 128 * 1024; ldc = 1024; m0 = 0; n0 = bx * 128; break;
    case 2:  A = BI;  B = Winvt; C = Hb;                ldc = 1024; m0 = 0; n0 = bx * 128; break;
    default: A = WOb; B = UcatT; C = Gfin;              ldc = 128;  m0 = bx * 128; n0 = 0; break;
  }
  gemm_body<2>(A, B, C, 1024, 1024, ldc, 1024, m0, n0, nullptr, nullptr, 0, 0, 128);
}

// G_P3 rows 0..63 -> Gcat rows 256..319 (s3); G_P4 rows 64..127 -> 320..383 (p4)
__global__ __launch_bounds__(256) void smallB_k(
    const unsigned short* Hb, const unsigned short* WKt, const unsigned short* WQt,
    unsigned short* Gcat)
{
  const int bx = blockIdx.x;
  const unsigned short* B = (blockIdx.y == 0) ? WKt : WQt;
  const int rlo = (blockIdx.y == 0) ? 0 : 64;
  gemm_body<2>(Hb, B, Gcat + 256 * 1024, 1024, 1024, 1024, 1024, 0, bx * 128,
               nullptr, nullptr, 0, rlo, rlo + 64);
}

// Pcat parts [2][8192][512] bf16 = xb @ Gcat^T split-K=2 + chunk sums
__global__ __launch_bounds__(256) void mainP_k(
    const unsigned short* __restrict__ xb, const unsigned short* __restrict__ Gcat,
    unsigned short* __restrict__ Pcat, float* __restrict__ sums)
{
  const int y = blockIdx.y, kz = blockIdx.z;
  gemm_body<4>(xb + kz * 512, Gcat + (size_t)y * 128 * 1024 + kz * 512,
               Pcat + (size_t)kz * BT_DIM * 512 + y * 128,
               1024, 1024, 512, 512, blockIdx.x * 128, 0,
               nullptr, sums + kz * 131072, y, 0, 128);
}

// out = rcat @ Gfin^T + obias  (M=8192, N=1024, K=128, fp32 out)
__global__ __launch_bounds__(256) void final_k(
    const unsigned short* __restrict__ rcat, const unsigned short* __restrict__ Gfin,
    const float* __restrict__ obias, float* __restrict__ out)
{
  gemm_body<3>(rcat, Gfin, out, 128, 128, 1024, 128,
               blockIdx.x * 128, blockIdx.y * 128, obias, nullptr, 0, 0, 128);
}

// ---------------------------------------------------------------------------
// Fused prep (range-dispatched on blockIdx.x)
// ---------------------------------------------------------------------------
__global__ __launch_bounds__(256) void prep_k(
    const float* __restrict__ x, const float* __restrict__ WQ,
    const float* __restrict__ WK, const float* __restrict__ WO,
    const float* __restrict__ Winv, const float* __restrict__ U_b,
    const float* __restrict__ V_b, const float* __restrict__ W_b,
    const float* __restrict__ bias_b, const float* __restrict__ U_t,
    const float* __restrict__ V_t, const float* __restrict__ W_t,
    const float* __restrict__ X_t, const float* __restrict__ bias_t,
    const float* __restrict__ abi_p, const float* __restrict__ atri_p,
    unsigned short* xb, unsigned short* WQt, unsigned short* WKt,
    unsigned short* Winvt, unsigned short* WOb, unsigned short* BQ,
    unsigned short* BK, unsigned short* BI, unsigned short* UcatT,
    unsigned short* Gcat, float* obias)
{
  __shared__ float smem[64 * 65];
  const int bx = blockIdx.x, tid = threadIdx.x;
  if (bx < 8192) {                        // x -> bf16
    int i = bx * 256 + tid;
    float4 v = ((const float4*)x)[i];
    ushort4 o; o.x = f2bf(v.x); o.y = f2bf(v.y); o.z = f2bf(v.z); o.w = f2bf(v.w);
    ((ushort4*)xb)[i] = o;
  } else if (bx < 8960) {                 // transpose+cast WQ/WK/Winv
    int local = bx - 8192;
    const float* s; unsigned short* d;
    switch (local >> 8) { case 0: s = WQ; d = WQt; break;
                          case 1: s = WK; d = WKt; break;
                          default: s = Winv; d = Winvt; break; }
    int t = local & 255;
    int tY = t >> 4, tX = t & 15;
    int c = tid & 63, g = tid >> 6;
#pragma unroll
    for (int rr = 0; rr < 16; ++rr) {
      int r = g * 16 + rr;
      smem[r * 65 + c] = s[(size_t)(tY * 64 + r) * 1024 + tX * 64 + c];
    }
    __syncthreads();
#pragma unroll
    for (int rr = 0; rr < 16; ++rr) {
      int r = g * 16 + rr;
      d[(size_t)(tX * 64 + r) * 1024 + tY * 64 + c] = f2bf(smem[c * 65 + r]);
    }
  } else if (bx < 10496) {                // BQ/BK/BI panels [128][1024]
    int local = bx - 8960;
    const float *s0, *s1; unsigned short* d;
    switch (local >> 9) { case 0: s0 = V_b; s1 = V_t; d = BQ; break;
                          case 1: s0 = W_b; s1 = W_t; d = BK; break;
                          default: s0 = V_b; s1 = W_b; d = BI; break; }
    int idx = (local & 511) * 256 + tid;
    int n = idx >> 10, k = idx & 1023;
    const float* s = (n < 64) ? s0 : s1;
    d[idx] = f2bf(s[k * 64 + (n & 63)]);
  } else if (bx < 11008) {                // UcatT[128][1024]
    int idx = (bx - 10496) * 256 + tid;
    int k = idx >> 10, dd = idx & 1023;
    UcatT[idx] = f2bf(k < 64 ? U_b[dd * 64 + k] : U_t[dd * 64 + k - 64]);
  } else if (bx < 11520) {                // Gcat rows 384..511 = X_t^T (dup)
    int idx = (bx - 11008) * 256 + tid;
    int r = idx >> 10, dd = idx & 1023;
    Gcat[(size_t)384 * 1024 + idx] = f2bf(X_t[dd * 64 + (r & 63)]);
  } else if (bx < 12544) {                // WO -> bf16
    int i = (bx - 11520) * 256 + tid;
    float4 v = ((const float4*)WO)[i];
    ushort4 o; o.x = f2bf(v.x); o.y = f2bf(v.y); o.z = f2bf(v.z); o.w = f2bf(v.w);
    ((ushort4*)WOb)[i] = o;
  } else {                                // obias[n]
    int n = bx - 12544;
    const float abi = abi_p[0], atri = atri_p[0];
    float s = 0.f;
    for (int d0 = tid; d0 < 1024; d0 += 256)
      s += ((1.f + abi) * bias_b[d0] + atri * bias_t[d0]) * WO[(size_t)n * 1024 + d0];
    smem[tid] = s;
    __syncthreads();
#pragma unroll
    for (int w = 128; w > 0; w >>= 1) {
      if (tid < w) smem[tid] += smem[tid + w];
      __syncthreads();
    }
    if (tid == 0) obias[n] = smem[0];
  }
}

// ---------------------------------------------------------------------------
// scanB: 16-row chunks (128 per batch), carry from mainP chunk sums (2 splits),
// combine -> rcat bf16. Pcat cols: 0:p1 64:p5 128:s2 192:s6 256:s3 320:p4 384:sZ
// ---------------------------------------------------------------------------
__global__ __launch_bounds__(256) void scanB_k(
    const unsigned short* __restrict__ P, const float* __restrict__ sums,
    const float* __restrict__ abi_p, const float* __restrict__ atri_p,
    unsigned short* __restrict__ rcat)
{
  const int w = blockIdx.x * 4 + (threadIdx.x >> 6);   // 0..511
  const int lane = threadIdx.x & 63;
  const int b = w >> 7, ch = w & 127;
  float c2 = 0.f, c6 = 0.f, c3 = 0.f, cZ = 0.f;
  for (int i = 0; i < ch; ++i) {
    const float* s0 = sums + ((((size_t)b << 7) + i) << 8) + lane;
    const float* s1 = s0 + 131072;
    c2 += s0[0]   + s1[0];
    c6 += s0[64]  + s1[64];
    c3 += s0[128] + s1[128];
    cZ += s0[192] + s1[192];
  }
  const float abi = abi_p[0], atri = atri_p[0];
  const size_t row0 = (size_t)b * T_LEN + ch * 16;
  const unsigned short* P1 = P + (size_t)BT_DIM * 512;
#pragma unroll 2
  for (int t = 0; t < 16; ++t) {
    const size_t ro = (row0 + t) * 512 + lane;
    const float p1 = bf2f(P[ro])       + bf2f(P1[ro]);
    const float p5 = bf2f(P[ro + 64])  + bf2f(P1[ro + 64]);
    c2            += bf2f(P[ro + 128]) + bf2f(P1[ro + 128]);
    c6            += bf2f(P[ro + 192]) + bf2f(P1[ro + 192]);
    c3            += bf2f(P[ro + 256]) + bf2f(P1[ro + 256]);
    const float p4 = bf2f(P[ro + 320]) + bf2f(P1[ro + 320]);
    cZ            += bf2f(P[ro + 384]) + bf2f(P1[ro + 384]);
    const float invc = 1.0f / (float)(ch * 16 + t + 1);
    const float rb = (p1 * c2 + abi * (c3 * p4)) * invc;
    const float rt = atri * p5 * c6 * cZ * invc * invc;
    const size_t rro = (row0 + t) * 128;
    rcat[rro + lane]      = f2bf(rb);
    rcat[rro + 64 + lane] = f2bf(rt);
  }
}

// ---------------------------------------------------------------------------
extern "C" void kernel_launch(void* const* d_in, const int* in_sizes, int n_in,
                              void* d_out, int out_size, void* d_ws, size_t ws_size,
                              hipStream_t stream)
{
  const float* x      = (const float*)d_in[0];
  const float* WQ     = (const float*)d_in[1];
  const float* WK     = (const float*)d_in[2];
  const float* WO     = (const float*)d_in[3];
  const float* Winv   = (const float*)d_in[4];
  const float* U_b    = (const float*)d_in[5];
  const float* V_b    = (const float*)d_in[6];
  const float* W_b    = (const float*)d_in[7];
  const float* bias_b = (const float*)d_in[8];
  const float* U_t    = (const float*)d_in[9];
  const float* V_t    = (const float*)d_in[10];
  const float* W_t    = (const float*)d_in[11];
  const float* X_t    = (const float*)d_in[12];
  const float* bias_t = (const float*)d_in[13];
  const float* a_bi   = (const float*)d_in[14];
  const float* a_tri  = (const float*)d_in[15];

  char* ws = (char*)d_ws;
  size_t off = 0;
  unsigned short* xb    = (unsigned short*)(ws + off); off += (size_t)BT_DIM * 1024 * 2;     // 16MB
  unsigned short* Pcat  = (unsigned short*)(ws + off); off += (size_t)2 * BT_DIM * 512 * 2;  // 16MB (2 splits)
  unsigned short* rcat  = (unsigned short*)(ws + off); off += (size_t)BT_DIM * 128 * 2;      // 2MB
  unsigned short* WQt   = (unsigned short*)(ws + off); off += 2097152;
  unsigned short* WKt   = (unsigned short*)(ws + off); off += 2097152;
  unsigned short* Winvt = (unsigned short*)(ws + off); off += 2097152;
  unsigned short* WOb   = (unsigned short*)(ws + off); off += 2097152;
  unsigned short* BQ    = (unsigned short*)(ws + off); off += 262144;
  unsigned short* BK    = (unsigned short*)(ws + off); off += 262144;
  unsigned short* BI    = (unsigned short*)(ws + off); off += 262144;
  unsigned short* Hb    = (unsigned short*)(ws + off); off += 262144;
  unsigned short* UcatT = (unsigned short*)(ws + off); off += 262144;
  unsigned short* Gcat  = (unsigned short*)(ws + off); off += (size_t)512 * 1024 * 2;        // 1MB
  unsigned short* Gfin  = (unsigned short*)(ws + off); off += 262144;
  float*          obias = (float*)(ws + off);          off += 4096;
  float*          sums  = (float*)(ws + off);          off += 1048576;  // 2 splits * 512 chunks * 256 f32

  prep_k<<<dim3(13568), 256, 0, stream>>>(x, WQ, WK, WO, Winv, U_b, V_b, W_b, bias_b,
                                          U_t, V_t, W_t, X_t, bias_t, a_bi, a_tri,
                                          xb, WQt, WKt, Winvt, WOb, BQ, BK, BI,
                                          UcatT, Gcat, obias);
  smallA_k<<<dim3(8, 4), 256, 0, stream>>>(BQ, BK, BI, WOb, WQt, WKt, Winvt, UcatT,
                                           Gcat, Hb, Gfin);
  smallB_k<<<dim3(8, 2), 256, 0, stream>>>(Hb, WKt, WQt, Gcat);
  mainP_k<<<dim3(64, 4, 2), 256, 0, stream>>>(xb, Gcat, Pcat, sums);
  scanB_k<<<dim3(128), 256, 0, stream>>>(Pcat, sums, a_bi, a_tri, rcat);
  final_k<<<dim3(64, 8), 256, 0, stream>>>(rcat, Gfin, obias, (float*)d_out);
}

// Round 6
// 194.619 us; speedup vs baseline: 1.1258x; 1.1258x over previous
//
#include <hip/hip_runtime.h>

#define T_LEN 2048
#define BT_DIM 8192  // B*T

typedef __attribute__((ext_vector_type(8))) short s16x8;
typedef __attribute__((ext_vector_type(4))) float f32x4;

typedef __attribute__((address_space(1))) void gvoid_t;
typedef __attribute__((address_space(3))) void svoid_t;

__device__ __forceinline__ unsigned short f2bf(float f) {
  unsigned int u = __builtin_bit_cast(unsigned int, f);
  u += 0x7fffu + ((u >> 16) & 1u);
  return (unsigned short)(u >> 16);
}
__device__ __forceinline__ float bf2f(unsigned short u) {
  unsigned int v = (unsigned int)u << 16;
  return __builtin_bit_cast(float, v);
}
__device__ __forceinline__ void gload16(const void* g, void* l) {
  __builtin_amdgcn_global_load_lds((gvoid_t*)g, (svoid_t*)l, 16, 0, 0);
}

// ---------------------------------------------------------------------------
// GEMM core: C[m,n] = sum_k A[m,k]*B[n,k], 128x128 tile, BK=64, 4 waves,
// 2-phase double-buffered LDS. T2 swizzle: LDS dest linear (gload_lds
// requirement), per-lane GLOBAL source col pre-swizzled, ds_read col XOR'd
// with the same involution -> 16-way conflict becomes 2-way (free).
// EPI: 2 = bf16 out, local-row window [rlo,rhi)
//      3 = f32 out + obias[col]
//      4 = bf16 out + per-16-row chunk column sums into `sums` (mainP)
// ---------------------------------------------------------------------------
template<int EPI>
__device__ __forceinline__ void gemm_body(
    const unsigned short* __restrict__ A, const unsigned short* __restrict__ B,
    void* __restrict__ Cv, int lda, int ldb, int ldc, int K, int m0, int n0,
    const float* __restrict__ obias, float* __restrict__ sums, int ygrp,
    int rlo, int rhi)
{
  __shared__ unsigned short As[2 * 128 * 64];   // 2 x 16KB
  __shared__ unsigned short Bs[2 * 128 * 64];
  const int tid  = threadIdx.x;
  const int wave = tid >> 6;
  const int lane = tid & 63;
  const int wr = wave >> 1, wc = wave & 1;
  const int trow = tid >> 3;                              // 0..31
  const int scol = (((tid & 7) ^ ((tid >> 3) & 7)) << 3); // swizzled k-col

  const unsigned short* Ap = A + (size_t)(m0 + trow) * lda + scol;
  const unsigned short* Bp = B + (size_t)(n0 + trow) * ldb + scol;

  f32x4 acc[4][4] = {};

  auto stage = [&](int buf, int kt) {
    char* ab = (char*)As + buf * 16384 + wave * 1024;
    char* bb = (char*)Bs + buf * 16384 + wave * 1024;
#pragma unroll
    for (int it = 0; it < 4; ++it) {
      gload16(Ap + (size_t)it * 32 * lda + kt, ab + it * 4096);
      gload16(Bp + (size_t)it * 32 * ldb + kt, bb + it * 4096);
    }
  };

  stage(0, 0);
  __syncthreads();
  int cur = 0;
  const int xr = (lane & 7) << 3;   // read-side XOR (elements)
  for (int kt = 64; kt <= K; kt += 64) {
    if (kt < K) stage(cur ^ 1, kt);     // prefetch next tile (overlaps MFMA)
#pragma unroll
    for (int ks = 0; ks < 2; ++ks) {
      const int kk = ((ks << 5) + ((lane >> 4) << 3)) ^ xr;
      const int ra = (wr << 6) + (lane & 15);
      const int rb = (wc << 6) + (lane & 15);
      s16x8 af[4], bfr[4];
#pragma unroll
      for (int i = 0; i < 4; ++i)
        af[i] = *(const s16x8*)&As[cur * 8192 + (ra + (i << 4)) * 64 + kk];
#pragma unroll
      for (int i = 0; i < 4; ++i)
        bfr[i] = *(const s16x8*)&Bs[cur * 8192 + (rb + (i << 4)) * 64 + kk];
#pragma unroll
      for (int i = 0; i < 4; ++i)
#pragma unroll
        for (int j = 0; j < 4; ++j)
          acc[i][j] = __builtin_amdgcn_mfma_f32_16x16x32_bf16(af[i], bfr[j], acc[i][j], 0, 0, 0);
    }
    __syncthreads();                    // drains vmcnt -> next buffer ready
    cur ^= 1;
  }

  // Epilogue. C/D layout (m89-verified): col = lane&15, row = (lane>>4)*4 + reg
  if (EPI == 2) {
    unsigned short* C = (unsigned short*)Cv;
#pragma unroll
    for (int i = 0; i < 4; ++i) {
      const int lr0 = (wr << 6) + (i << 4) + ((lane >> 4) << 2);
#pragma unroll
      for (int j = 0; j < 4; ++j) {
        const int c = n0 + (wc << 6) + (j << 4) + (lane & 15);
#pragma unroll
        for (int rr = 0; rr < 4; ++rr) {
          const int lr = lr0 + rr;
          if (lr >= rlo && lr < rhi)
            C[(size_t)(m0 + lr) * ldc + c] = f2bf(acc[i][j][rr]);
        }
      }
    }
  } else if (EPI == 3) {
    float* C = (float*)Cv;
    float ob[4];
#pragma unroll
    for (int j = 0; j < 4; ++j)
      ob[j] = obias[n0 + (wc << 6) + (j << 4) + (lane & 15)];
#pragma unroll
    for (int i = 0; i < 4; ++i) {
      const int r0 = m0 + (wr << 6) + (i << 4) + ((lane >> 4) << 2);
#pragma unroll
      for (int j = 0; j < 4; ++j) {
        const int c = n0 + (wc << 6) + (j << 4) + (lane & 15);
#pragma unroll
        for (int rr = 0; rr < 4; ++rr)
          C[(size_t)(r0 + rr) * ldc + c] = acc[i][j][rr] + ob[j];
      }
    }
  } else {  // EPI == 4: bf16 out (n0==0) + per-16-row-chunk column sums
    unsigned short* C = (unsigned short*)Cv;
#pragma unroll
    for (int i = 0; i < 4; ++i) {
      const int r0 = m0 + (wr << 6) + (i << 4) + ((lane >> 4) << 2);
#pragma unroll
      for (int j = 0; j < 4; ++j) {
        const int c = (wc << 6) + (j << 4) + (lane & 15);
#pragma unroll
        for (int rr = 0; rr < 4; ++rr)
          C[(size_t)(r0 + rr) * ldc + c] = f2bf(acc[i][j][rr]);
      }
    }
    // streams: y=1: wc0->s2(off0), wc1->s6(off64); y=2 wc0->s3(off128); y=3 wc0->sZ(off192)
    int soff = -1;
    if (ygrp == 1) soff = wc << 6;
    else if (ygrp == 2 && wc == 0) soff = 128;
    else if (ygrp == 3 && wc == 0) soff = 192;
    if (soff >= 0) {
#pragma unroll
      for (int i = 0; i < 4; ++i) {     // each i = one 16-row chunk
        const int R0 = m0 + (wr << 6) + (i << 4);
        const int b_ = R0 >> 11, ch = (R0 & 2047) >> 4;
#pragma unroll
        for (int j = 0; j < 4; ++j) {
          float v = acc[i][j][0] + acc[i][j][1] + acc[i][j][2] + acc[i][j][3];
          v += __shfl_xor(v, 16);
          v += __shfl_xor(v, 32);
          if (lane < 16)
            sums[(((b_ << 7) + ch) << 8) + soff + (j << 4) + lane] = v;
        }
      }
    }
  }
}

// ---------------------------------------------------------------------------
// Weight folds
// ---------------------------------------------------------------------------
__global__ __launch_bounds__(256) void smallA_k(
    const unsigned short* BQ, const unsigned short* BK, const unsigned short* BI,
    const unsigned short* WOb, const unsigned short* WQt, const unsigned short* WKt,
    const unsigned short* Winvt, const unsigned short* UcatT,
    unsigned short* Gcat, unsigned short* Hb, unsigned short* Gfin)
{
  const int bx = blockIdx.x;
  const unsigned short *A, *B; unsigned short* C; int ldc, m0, n0;
  switch (blockIdx.y) {
    case 0:  A = BQ;  B = WQt;   C = Gcat;              ldc = 1024; m0 = 0; n0 = bx * 128; break;
    case 1:  A = BK;  B = WKt;   C = Gcat + 128 * 1024; ldc = 1024; m0 = 0; n0 = bx * 128; break;
    case 2:  A = BI;  B = Winvt; C = Hb;                ldc = 1024; m0 = 0; n0 = bx * 128; break;
    default: A = WOb; B = UcatT; C = Gfin;              ldc = 128;  m0 = bx * 128; n0 = 0; break;
  }
  gemm_body<2>(A, B, C, 1024, 1024, ldc, 1024, m0, n0, nullptr, nullptr, 0, 0, 128);
}

// G_P3 rows 0..63 -> Gcat rows 256..319 (s3); G_P4 rows 64..127 -> 320..383 (p4)
__global__ __launch_bounds__(256) void smallB_k(
    const unsigned short* Hb, const unsigned short* WKt, const unsigned short* WQt,
    unsigned short* Gcat)
{
  const int bx = blockIdx.x;
  const unsigned short* B = (blockIdx.y == 0) ? WKt : WQt;
  const int rlo = (blockIdx.y == 0) ? 0 : 64;
  gemm_body<2>(Hb, B, Gcat + 256 * 1024, 1024, 1024, 1024, 1024, 0, bx * 128,
               nullptr, nullptr, 0, rlo, rlo + 64);
}

// Pcat parts [2][8192][512] bf16 = xb @ Gcat^T split-K=2 + chunk sums
__global__ __launch_bounds__(256) void mainP_k(
    const unsigned short* __restrict__ xb, const unsigned short* __restrict__ Gcat,
    unsigned short* __restrict__ Pcat, float* __restrict__ sums)
{
  const int y = blockIdx.y, kz = blockIdx.z;
  gemm_body<4>(xb + kz * 512, Gcat + (size_t)y * 128 * 1024 + kz * 512,
               Pcat + (size_t)kz * BT_DIM * 512 + y * 128,
               1024, 1024, 512, 512, blockIdx.x * 128, 0,
               nullptr, sums + kz * 131072, y, 0, 128);
}

// out = rcat @ Gfin^T + obias  (M=8192, N=1024, K=128, fp32 out)
__global__ __launch_bounds__(256) void final_k(
    const unsigned short* __restrict__ rcat, const unsigned short* __restrict__ Gfin,
    const float* __restrict__ obias, float* __restrict__ out)
{
  gemm_body<3>(rcat, Gfin, out, 128, 128, 1024, 128,
               blockIdx.x * 128, blockIdx.y * 128, obias, nullptr, 0, 0, 128);
}

// ---------------------------------------------------------------------------
// Fused prep (range-dispatched on blockIdx.x)
// ---------------------------------------------------------------------------
__global__ __launch_bounds__(256) void prep_k(
    const float* __restrict__ x, const float* __restrict__ WQ,
    const float* __restrict__ WK, const float* __restrict__ WO,
    const float* __restrict__ Winv, const float* __restrict__ U_b,
    const float* __restrict__ V_b, const float* __restrict__ W_b,
    const float* __restrict__ bias_b, const float* __restrict__ U_t,
    const float* __restrict__ V_t, const float* __restrict__ W_t,
    const float* __restrict__ X_t, const float* __restrict__ bias_t,
    const float* __restrict__ abi_p, const float* __restrict__ atri_p,
    unsigned short* xb, unsigned short* WQt, unsigned short* WKt,
    unsigned short* Winvt, unsigned short* WOb, unsigned short* BQ,
    unsigned short* BK, unsigned short* BI, unsigned short* UcatT,
    unsigned short* Gcat, float* obias)
{
  __shared__ float smem[64 * 65];
  const int bx = blockIdx.x, tid = threadIdx.x;
  if (bx < 8192) {                        // x -> bf16
    int i = bx * 256 + tid;
    float4 v = ((const float4*)x)[i];
    ushort4 o; o.x = f2bf(v.x); o.y = f2bf(v.y); o.z = f2bf(v.z); o.w = f2bf(v.w);
    ((ushort4*)xb)[i] = o;
  } else if (bx < 8960) {                 // transpose+cast WQ/WK/Winv
    int local = bx - 8192;
    const float* s; unsigned short* d;
    switch (local >> 8) { case 0: s = WQ; d = WQt; break;
                          case 1: s = WK; d = WKt; break;
                          default: s = Winv; d = Winvt; break; }
    int t = local & 255;
    int tY = t >> 4, tX = t & 15;
    int c = tid & 63, g = tid >> 6;
#pragma unroll
    for (int rr = 0; rr < 16; ++rr) {
      int r = g * 16 + rr;
      smem[r * 65 + c] = s[(size_t)(tY * 64 + r) * 1024 + tX * 64 + c];
    }
    __syncthreads();
#pragma unroll
    for (int rr = 0; rr < 16; ++rr) {
      int r = g * 16 + rr;
      d[(size_t)(tX * 64 + r) * 1024 + tY * 64 + c] = f2bf(smem[c * 65 + r]);
    }
  } else if (bx < 10496) {                // BQ/BK/BI panels [128][1024]
    int local = bx - 8960;
    const float *s0, *s1; unsigned short* d;
    switch (local >> 9) { case 0: s0 = V_b; s1 = V_t; d = BQ; break;
                          case 1: s0 = W_b; s1 = W_t; d = BK; break;
                          default: s0 = V_b; s1 = W_b; d = BI; break; }
    int idx = (local & 511) * 256 + tid;
    int n = idx >> 10, k = idx & 1023;
    const float* s = (n < 64) ? s0 : s1;
    d[idx] = f2bf(s[k * 64 + (n & 63)]);
  } else if (bx < 11008) {                // UcatT[128][1024]
    int idx = (bx - 10496) * 256 + tid;
    int k = idx >> 10, dd = idx & 1023;
    UcatT[idx] = f2bf(k < 64 ? U_b[dd * 64 + k] : U_t[dd * 64 + k - 64]);
  } else if (bx < 11520) {                // Gcat rows 384..511 = X_t^T (dup)
    int idx = (bx - 11008) * 256 + tid;
    int r = idx >> 10, dd = idx & 1023;
    Gcat[(size_t)384 * 1024 + idx] = f2bf(X_t[dd * 64 + (r & 63)]);
  } else if (bx < 12544) {                // WO -> bf16
    int i = (bx - 11520) * 256 + tid;
    float4 v = ((const float4*)WO)[i];
    ushort4 o; o.x = f2bf(v.x); o.y = f2bf(v.y); o.z = f2bf(v.z); o.w = f2bf(v.w);
    ((ushort4*)WOb)[i] = o;
  } else {                                // obias[n]
    int n = bx - 12544;
    const float abi = abi_p[0], atri = atri_p[0];
    float s = 0.f;
    for (int d0 = tid; d0 < 1024; d0 += 256)
      s += ((1.f + abi) * bias_b[d0] + atri * bias_t[d0]) * WO[(size_t)n * 1024 + d0];
    smem[tid] = s;
    __syncthreads();
#pragma unroll
    for (int w = 128; w > 0; w >>= 1) {
      if (tid < w) smem[tid] += smem[tid + w];
      __syncthreads();
    }
    if (tid == 0) obias[n] = smem[0];
  }
}

// ---------------------------------------------------------------------------
// scanC: parallel exclusive prefix over the 128 chunk sums (both splits added)
// per (b, col). One wave per (b,col); lanes = chunk pairs; shfl_up scan.
// carry[b][ch][col] (col spans all 4 streams' 256-wide space).
// ---------------------------------------------------------------------------
__global__ __launch_bounds__(256) void scanC_k(const float* __restrict__ sums,
                                               float* __restrict__ carry)
{
  const int W = blockIdx.x * 4 + (threadIdx.x >> 6);   // 0..1023
  const int lane = threadIdx.x & 63;
  const int b = W >> 8, col = W & 255;
  const int ch0 = lane << 1;
  const size_t i0 = ((((size_t)b << 7) + ch0) << 8) + col;
  const size_t i1 = i0 + 256;
  const float v0 = sums[i0] + sums[i0 + 131072];
  const float v1 = sums[i1] + sums[i1 + 131072];
  float a = v0 + v1;
#pragma unroll
  for (int off = 1; off < 64; off <<= 1) {
    const float u = __shfl_up(a, off);
    if (lane >= off) a += u;
  }
  const float excl = a - (v0 + v1);   // exclusive prefix for chunk ch0
  carry[i0] = excl;
  carry[i1] = excl + v0;
}

// ---------------------------------------------------------------------------
// scanB: 16-row chunks, carry preloaded from scanC, combine -> rcat bf16.
// Pcat cols: 0:p1 64:p5 128:s2 192:s6 256:s3 320:p4 384:sZ (per split)
// ---------------------------------------------------------------------------
__global__ __launch_bounds__(256) void scanB_k(
    const unsigned short* __restrict__ P, const float* __restrict__ carry,
    const float* __restrict__ abi_p, const float* __restrict__ atri_p,
    unsigned short* __restrict__ rcat)
{
  const int w = blockIdx.x * 4 + (threadIdx.x >> 6);   // 0..511
  const int lane = threadIdx.x & 63;
  const int b = w >> 7, ch = w & 127;
  const float* cp = carry + ((((size_t)b << 7) + ch) << 8) + lane;
  float c2 = cp[0], c6 = cp[64], c3 = cp[128], cZ = cp[192];
  const float abi = abi_p[0], atri = atri_p[0];
  const size_t row0 = (size_t)b * T_LEN + ch * 16;
  const unsigned short* P1 = P + (size_t)BT_DIM * 512;
#pragma unroll 4
  for (int t = 0; t < 16; ++t) {
    const size_t ro = (row0 + t) * 512 + lane;
    const float p1 = bf2f(P[ro])       + bf2f(P1[ro]);
    const float p5 = bf2f(P[ro + 64])  + bf2f(P1[ro + 64]);
    c2            += bf2f(P[ro + 128]) + bf2f(P1[ro + 128]);
    c6            += bf2f(P[ro + 192]) + bf2f(P1[ro + 192]);
    c3            += bf2f(P[ro + 256]) + bf2f(P1[ro + 256]);
    const float p4 = bf2f(P[ro + 320]) + bf2f(P1[ro + 320]);
    cZ            += bf2f(P[ro + 384]) + bf2f(P1[ro + 384]);
    const float invc = 1.0f / (float)(ch * 16 + t + 1);
    const float rb = (p1 * c2 + abi * (c3 * p4)) * invc;
    const float rt = atri * p5 * c6 * cZ * invc * invc;
    const size_t rro = (row0 + t) * 128;
    rcat[rro + lane]      = f2bf(rb);
    rcat[rro + 64 + lane] = f2bf(rt);
  }
}

// ---------------------------------------------------------------------------
extern "C" void kernel_launch(void* const* d_in, const int* in_sizes, int n_in,
                              void* d_out, int out_size, void* d_ws, size_t ws_size,
                              hipStream_t stream)
{
  const float* x      = (const float*)d_in[0];
  const float* WQ     = (const float*)d_in[1];
  const float* WK     = (const float*)d_in[2];
  const float* WO     = (const float*)d_in[3];
  const float* Winv   = (const float*)d_in[4];
  const float* U_b    = (const float*)d_in[5];
  const float* V_b    = (const float*)d_in[6];
  const float* W_b    = (const float*)d_in[7];
  const float* bias_b = (const float*)d_in[8];
  const float* U_t    = (const float*)d_in[9];
  const float* V_t    = (const float*)d_in[10];
  const float* W_t    = (const float*)d_in[11];
  const float* X_t    = (const float*)d_in[12];
  const float* bias_t = (const float*)d_in[13];
  const float* a_bi   = (const float*)d_in[14];
  const float* a_tri  = (const float*)d_in[15];

  char* ws = (char*)d_ws;
  size_t off = 0;
  unsigned short* xb    = (unsigned short*)(ws + off); off += (size_t)BT_DIM * 1024 * 2;     // 16MB
  unsigned short* Pcat  = (unsigned short*)(ws + off); off += (size_t)2 * BT_DIM * 512 * 2;  // 16MB (2 splits)
  unsigned short* rcat  = (unsigned short*)(ws + off); off += (size_t)BT_DIM * 128 * 2;      // 2MB
  unsigned short* WQt   = (unsigned short*)(ws + off); off += 2097152;
  unsigned short* WKt   = (unsigned short*)(ws + off); off += 2097152;
  unsigned short* Winvt = (unsigned short*)(ws + off); off += 2097152;
  unsigned short* WOb   = (unsigned short*)(ws + off); off += 2097152;
  unsigned short* BQ    = (unsigned short*)(ws + off); off += 262144;
  unsigned short* BK    = (unsigned short*)(ws + off); off += 262144;
  unsigned short* BI    = (unsigned short*)(ws + off); off += 262144;
  unsigned short* Hb    = (unsigned short*)(ws + off); off += 262144;
  unsigned short* UcatT = (unsigned short*)(ws + off); off += 262144;
  unsigned short* Gcat  = (unsigned short*)(ws + off); off += (size_t)512 * 1024 * 2;        // 1MB
  unsigned short* Gfin  = (unsigned short*)(ws + off); off += 262144;
  float*          obias = (float*)(ws + off);          off += 4096;
  float*          sums  = (float*)(ws + off);          off += 1048576;  // 2 splits * 512 chunks * 256 f32
  float*          carry = (float*)(ws + off);          off += 524288;   // 4b * 128ch * 256 f32

  prep_k<<<dim3(13568), 256, 0, stream>>>(x, WQ, WK, WO, Winv, U_b, V_b, W_b, bias_b,
                                          U_t, V_t, W_t, X_t, bias_t, a_bi, a_tri,
                                          xb, WQt, WKt, Winvt, WOb, BQ, BK, BI,
                                          UcatT, Gcat, obias);
  smallA_k<<<dim3(8, 4), 256, 0, stream>>>(BQ, BK, BI, WOb, WQt, WKt, Winvt, UcatT,
                                           Gcat, Hb, Gfin);
  smallB_k<<<dim3(8, 2), 256, 0, stream>>>(Hb, WKt, WQt, Gcat);
  mainP_k<<<dim3(64, 4, 2), 256, 0, stream>>>(xb, Gcat, Pcat, sums);
  scanC_k<<<dim3(256), 256, 0, stream>>>(sums, carry);
  scanB_k<<<dim3(128), 256, 0, stream>>>(Pcat, carry, a_bi, a_tri, rcat);
  final_k<<<dim3(64, 8), 256, 0, stream>>>(rcat, Gfin, obias, (float*)d_out);
}

// Round 9
// 187.924 us; speedup vs baseline: 1.1659x; 1.0356x over previous
//
#include <hip/hip_runtime.h>

#define T_LEN 2048
#define BT_DIM 8192  // B*T

typedef __attribute__((ext_vector_type(8))) short s16x8;
typedef __attribute__((ext_vector_type(4))) float f32x4;

typedef __attribute__((address_space(1))) void gvoid_t;
typedef __attribute__((address_space(3))) void svoid_t;

__device__ __forceinline__ unsigned short f2bf(float f) {
  unsigned int u = __builtin_bit_cast(unsigned int, f);
  u += 0x7fffu + ((u >> 16) & 1u);
  return (unsigned short)(u >> 16);
}
__device__ __forceinline__ float bf2f(unsigned short u) {
  unsigned int v = (unsigned int)u << 16;
  return __builtin_bit_cast(float, v);
}
__device__ __forceinline__ void gload16(const void* g, void* l) {
  __builtin_amdgcn_global_load_lds((gvoid_t*)g, (svoid_t*)l, 16, 0, 0);
}

// ---------------------------------------------------------------------------
// GEMM core (BK=64): C[m,n] = sum_k A[m,k]*B[n,k], 128x128 tile, 4 waves,
// 2-phase double-buffered LDS, T2 swizzle both-sides. PROVEN (R6).
// EPI: 4 = bf16 out (n0==0) + per-16-row chunk column sums into `sums`
// ---------------------------------------------------------------------------
template<int EPI>
__device__ __forceinline__ void gemm_body(
    const unsigned short* __restrict__ A, const unsigned short* __restrict__ B,
    void* __restrict__ Cv, int lda, int ldb, int ldc, int K, int m0, int n0,
    const float* __restrict__ obias, float* __restrict__ sums, int ygrp,
    int rlo, int rhi)
{
  __shared__ unsigned short As[2 * 128 * 64];   // 2 x 16KB
  __shared__ unsigned short Bs[2 * 128 * 64];
  const int tid  = threadIdx.x;
  const int wave = tid >> 6;
  const int lane = tid & 63;
  const int wr = wave >> 1, wc = wave & 1;
  const int trow = tid >> 3;                              // 0..31
  const int scol = (((tid & 7) ^ ((tid >> 3) & 7)) << 3); // swizzled k-col

  const unsigned short* Ap = A + (size_t)(m0 + trow) * lda + scol;
  const unsigned short* Bp = B + (size_t)(n0 + trow) * ldb + scol;

  f32x4 acc[4][4] = {};

  auto stage = [&](int buf, int kt) {
    char* ab = (char*)As + buf * 16384 + wave * 1024;
    char* bb = (char*)Bs + buf * 16384 + wave * 1024;
#pragma unroll
    for (int it = 0; it < 4; ++it) {
      gload16(Ap + (size_t)it * 32 * lda + kt, ab + it * 4096);
      gload16(Bp + (size_t)it * 32 * ldb + kt, bb + it * 4096);
    }
  };

  stage(0, 0);
  __syncthreads();
  int cur = 0;
  const int xr = (lane & 7) << 3;   // read-side XOR (elements)
  for (int kt = 64; kt <= K; kt += 64) {
    if (kt < K) stage(cur ^ 1, kt);     // prefetch next tile (overlaps MFMA)
#pragma unroll
    for (int ks = 0; ks < 2; ++ks) {
      const int kk = ((ks << 5) + ((lane >> 4) << 3)) ^ xr;
      const int ra = (wr << 6) + (lane & 15);
      const int rb = (wc << 6) + (lane & 15);
      s16x8 af[4], bfr[4];
#pragma unroll
      for (int i = 0; i < 4; ++i)
        af[i] = *(const s16x8*)&As[cur * 8192 + (ra + (i << 4)) * 64 + kk];
#pragma unroll
      for (int i = 0; i < 4; ++i)
        bfr[i] = *(const s16x8*)&Bs[cur * 8192 + (rb + (i << 4)) * 64 + kk];
#pragma unroll
      for (int i = 0; i < 4; ++i)
#pragma unroll
        for (int j = 0; j < 4; ++j)
          acc[i][j] = __builtin_amdgcn_mfma_f32_16x16x32_bf16(af[i], bfr[j], acc[i][j], 0, 0, 0);
    }
    __syncthreads();                    // drains vmcnt -> next buffer ready
    cur ^= 1;
  }

  // Epilogue (EPI==4 only used here). C/D layout: col=lane&15, row=(lane>>4)*4+reg
  {
    unsigned short* C = (unsigned short*)Cv;
#pragma unroll
    for (int i = 0; i < 4; ++i) {
      const int r0 = m0 + (wr << 6) + (i << 4) + ((lane >> 4) << 2);
#pragma unroll
      for (int j = 0; j < 4; ++j) {
        const int c = (wc << 6) + (j << 4) + (lane & 15);
#pragma unroll
        for (int rr = 0; rr < 4; ++rr)
          C[(size_t)(r0 + rr) * ldc + c] = f2bf(acc[i][j][rr]);
      }
    }
    // streams: y=1: wc0->s2(off0), wc1->s6(off64); y=2 wc0->s3(off128); y=3 wc0->sZ(off192)
    int soff = -1;
    if (ygrp == 1) soff = wc << 6;
    else if (ygrp == 2 && wc == 0) soff = 128;
    else if (ygrp == 3 && wc == 0) soff = 192;
    if (soff >= 0) {
#pragma unroll
      for (int i = 0; i < 4; ++i) {     // each i = one 16-row chunk
        const int R0 = m0 + (wr << 6) + (i << 4);
        const int b_ = R0 >> 11, ch = (R0 & 2047) >> 4;
#pragma unroll
        for (int j = 0; j < 4; ++j) {
          float v = acc[i][j][0] + acc[i][j][1] + acc[i][j][2] + acc[i][j][3];
          v += __shfl_xor(v, 16);
          v += __shfl_xor(v, 32);
          if (lane < 16)
            sums[(((b_ << 7) + ch) << 8) + soff + (j << 4) + lane] = v;
        }
      }
    }
  }
}

// ---------------------------------------------------------------------------
// GEMM core (BK=128) for latency-bound small GEMMs (folds, final): halves
// the serial K-step count (16 -> 8 for K=1024; 1 step for K=128).
// LDS 128KB/block (1 block/CU -- fine, these launches are <=48 blocks).
// Swizzle (both-sides involution): LDS[row][g] = G[row][g^(row&15)];
// read G[row][kgrp] at LDS[row][kgrp^(row&15)], row&15 == lane&15.
// EPI: 2 = bf16 out, local-row window [rlo,rhi); 3 = f32 out + obias[col]
// ---------------------------------------------------------------------------
template<int EPI>
__device__ __forceinline__ void gemm_fold(
    const unsigned short* __restrict__ A, const unsigned short* __restrict__ B,
    void* __restrict__ Cv, int lda, int ldb, int ldc, int K, int m0, int n0,
    const float* __restrict__ obias, int rlo, int rhi)
{
  __shared__ unsigned short As[2 * 128 * 128];   // 2 x 32KB
  __shared__ unsigned short Bs[2 * 128 * 128];
  const int tid  = threadIdx.x;
  const int wave = tid >> 6;
  const int lane = tid & 63;
  const int wr = wave >> 1, wc = wave & 1;
  const int trow = tid >> 4;                               // 0..15
  const int scol = (((tid & 15) ^ ((tid >> 4) & 15)) << 3); // pre-swizzled col

  const unsigned short* Ap = A + (size_t)(m0 + trow) * lda + scol;
  const unsigned short* Bp = B + (size_t)(n0 + trow) * ldb + scol;

  f32x4 acc[4][4] = {};

  auto stage = [&](int buf, int kt) {
    // dest = wave*1024 + lane*16 per it (linear, gload_lds requirement)
    char* ab = (char*)As + buf * 32768 + wave * 1024;
    char* bb = (char*)Bs + buf * 32768 + wave * 1024;
#pragma unroll
    for (int it = 0; it < 8; ++it) {
      gload16(Ap + (size_t)(it * 16) * lda + kt, ab + it * 4096);
      gload16(Bp + (size_t)(it * 16) * ldb + kt, bb + it * 4096);
    }
  };

  stage(0, 0);
  __syncthreads();
  int cur = 0;
  for (int kt = 128; kt <= K; kt += 128) {
    if (kt < K) stage(cur ^ 1, kt);     // prefetch next tile
#pragma unroll
    for (int ks = 0; ks < 4; ++ks) {
      const int kk = (((ks << 2) + (lane >> 4)) ^ (lane & 15)) << 3;
      const int ra = (wr << 6) + (lane & 15);
      const int rb = (wc << 6) + (lane & 15);
      s16x8 af[4], bfr[4];
#pragma unroll
      for (int i = 0; i < 4; ++i)
        af[i] = *(const s16x8*)&As[cur * 16384 + (ra + (i << 4)) * 128 + kk];
#pragma unroll
      for (int i = 0; i < 4; ++i)
        bfr[i] = *(const s16x8*)&Bs[cur * 16384 + (rb + (i << 4)) * 128 + kk];
#pragma unroll
      for (int i = 0; i < 4; ++i)
#pragma unroll
        for (int j = 0; j < 4; ++j)
          acc[i][j] = __builtin_amdgcn_mfma_f32_16x16x32_bf16(af[i], bfr[j], acc[i][j], 0, 0, 0);
    }
    __syncthreads();
    cur ^= 1;
  }

  if (EPI == 2) {
    unsigned short* C = (unsigned short*)Cv;
#pragma unroll
    for (int i = 0; i < 4; ++i) {
      const int lr0 = (wr << 6) + (i << 4) + ((lane >> 4) << 2);
#pragma unroll
      for (int j = 0; j < 4; ++j) {
        const int c = n0 + (wc << 6) + (j << 4) + (lane & 15);
#pragma unroll
        for (int rr = 0; rr < 4; ++rr) {
          const int lr = lr0 + rr;
          if (lr >= rlo && lr < rhi)
            C[(size_t)(m0 + lr) * ldc + c] = f2bf(acc[i][j][rr]);
        }
      }
    }
  } else {  // EPI == 3
    float* C = (float*)Cv;
    float ob[4];
#pragma unroll
    for (int j = 0; j < 4; ++j)
      ob[j] = obias[n0 + (wc << 6) + (j << 4) + (lane & 15)];
#pragma unroll
    for (int i = 0; i < 4; ++i) {
      const int r0 = m0 + (wr << 6) + (i << 4) + ((lane >> 4) << 2);
#pragma unroll
      for (int j = 0; j < 4; ++j) {
        const int c = n0 + (wc << 6) + (j << 4) + (lane & 15);
#pragma unroll
        for (int rr = 0; rr < 4; ++rr)
          C[(size_t)(r0 + rr) * ldc + c] = acc[i][j][rr] + ob[j];
      }
    }
  }
}

// ---------------------------------------------------------------------------
// Weight folds (two launches, stream-ordered dependency -- NO device sync)
// ---------------------------------------------------------------------------
__global__ __launch_bounds__(256) void smallA_k(
    const unsigned short* BQ, const unsigned short* BK, const unsigned short* BI,
    const unsigned short* WOb, const unsigned short* WQt, const unsigned short* WKt,
    const unsigned short* Winvt, const unsigned short* UcatT,
    unsigned short* Gcat, unsigned short* Hb, unsigned short* Gfin)
{
  const int bx = blockIdx.x;
  const unsigned short *A, *B; unsigned short* C; int ldc = 1024, m0 = 0, n0 = bx * 128;
  switch (blockIdx.y) {
    case 0:  A = BQ;  B = WQt;   C = Gcat;              break;
    case 1:  A = BK;  B = WKt;   C = Gcat + 128 * 1024; break;
    case 2:  A = BI;  B = Winvt; C = Hb;                break;
    default: A = WOb; B = UcatT; C = Gfin; ldc = 128; m0 = bx * 128; n0 = 0; break;
  }
  gemm_fold<2>(A, B, C, 1024, 1024, ldc, 1024, m0, n0, nullptr, 0, 128);
}

// G_P3 rows 0..63 -> Gcat rows 256..319 (s3); G_P4 rows 64..127 -> 320..383 (p4)
__global__ __launch_bounds__(256) void smallB_k(
    const unsigned short* Hb, const unsigned short* WKt, const unsigned short* WQt,
    unsigned short* Gcat)
{
  const int bx = blockIdx.x;
  const unsigned short* B = (blockIdx.y == 0) ? WKt : WQt;
  const int rlo = (blockIdx.y == 0) ? 0 : 64;
  gemm_fold<2>(Hb, B, Gcat + 256 * 1024, 1024, 1024, 1024, 1024, 0, bx * 128,
               nullptr, rlo, rlo + 64);
}

// Pcat parts [2][8192][512] bf16 = xb @ Gcat^T split-K=2 + chunk sums
__global__ __launch_bounds__(256) void mainP_k(
    const unsigned short* __restrict__ xb, const unsigned short* __restrict__ Gcat,
    unsigned short* __restrict__ Pcat, float* __restrict__ sums)
{
  const int y = blockIdx.y, kz = blockIdx.z;
  gemm_body<4>(xb + kz * 512, Gcat + (size_t)y * 128 * 1024 + kz * 512,
               Pcat + (size_t)kz * BT_DIM * 512 + y * 128,
               1024, 1024, 512, 512, blockIdx.x * 128, 0,
               nullptr, sums + kz * 131072, y, 0, 128);
}

// out = rcat @ Gfin^T + obias  (M=8192, N=1024, K=128 -> single BK=128 step)
__global__ __launch_bounds__(256) void final_k(
    const unsigned short* __restrict__ rcat, const unsigned short* __restrict__ Gfin,
    const float* __restrict__ obias, float* __restrict__ out)
{
  gemm_fold<3>(rcat, Gfin, out, 128, 128, 1024, 128,
               blockIdx.x * 128, blockIdx.y * 128, obias, 0, 128);
}

// ---------------------------------------------------------------------------
// Fused prep (range-dispatched on blockIdx.x)
// ---------------------------------------------------------------------------
__global__ __launch_bounds__(256) void prep_k(
    const float* __restrict__ x, const float* __restrict__ WQ,
    const float* __restrict__ WK, const float* __restrict__ WO,
    const float* __restrict__ Winv, const float* __restrict__ U_b,
    const float* __restrict__ V_b, const float* __restrict__ W_b,
    const float* __restrict__ bias_b, const float* __restrict__ U_t,
    const float* __restrict__ V_t, const float* __restrict__ W_t,
    const float* __restrict__ X_t, const float* __restrict__ bias_t,
    const float* __restrict__ abi_p, const float* __restrict__ atri_p,
    unsigned short* xb, unsigned short* WQt, unsigned short* WKt,
    unsigned short* Winvt, unsigned short* WOb, unsigned short* BQ,
    unsigned short* BK, unsigned short* BI, unsigned short* UcatT,
    unsigned short* Gcat, float* obias)
{
  __shared__ float smem[64 * 65];
  const int bx = blockIdx.x, tid = threadIdx.x;
  if (bx < 8192) {                        // x -> bf16
    int i = bx * 256 + tid;
    float4 v = ((const float4*)x)[i];
    ushort4 o; o.x = f2bf(v.x); o.y = f2bf(v.y); o.z = f2bf(v.z); o.w = f2bf(v.w);
    ((ushort4*)xb)[i] = o;
  } else if (bx < 8960) {                 // transpose+cast WQ/WK/Winv
    int local = bx - 8192;
    const float* s; unsigned short* d;
    switch (local >> 8) { case 0: s = WQ; d = WQt; break;
                          case 1: s = WK; d = WKt; break;
                          default: s = Winv; d = Winvt; break; }
    int t = local & 255;
    int tY = t >> 4, tX = t & 15;
    int c = tid & 63, g = tid >> 6;
#pragma unroll
    for (int rr = 0; rr < 16; ++rr) {
      int r = g * 16 + rr;
      smem[r * 65 + c] = s[(size_t)(tY * 64 + r) * 1024 + tX * 64 + c];
    }
    __syncthreads();
#pragma unroll
    for (int rr = 0; rr < 16; ++rr) {
      int r = g * 16 + rr;
      d[(size_t)(tX * 64 + r) * 1024 + tY * 64 + c] = f2bf(smem[c * 65 + r]);
    }
  } else if (bx < 10496) {                // BQ/BK/BI panels [128][1024]
    int local = bx - 8960;
    const float *s0, *s1; unsigned short* d;
    switch (local >> 9) { case 0: s0 = V_b; s1 = V_t; d = BQ; break;
                          case 1: s0 = W_b; s1 = W_t; d = BK; break;
                          default: s0 = V_b; s1 = W_b; d = BI; break; }
    int idx = (local & 511) * 256 + tid;
    int n = idx >> 10, k = idx & 1023;
    const float* s = (n < 64) ? s0 : s1;
    d[idx] = f2bf(s[k * 64 + (n & 63)]);
  } else if (bx < 11008) {                // UcatT[128][1024]
    int idx = (bx - 10496) * 256 + tid;
    int k = idx >> 10, dd = idx & 1023;
    UcatT[idx] = f2bf(k < 64 ? U_b[dd * 64 + k] : U_t[dd * 64 + k - 64]);
  } else if (bx < 11520) {                // Gcat rows 384..511 = X_t^T (dup)
    int idx = (bx - 11008) * 256 + tid;
    int r = idx >> 10, dd = idx & 1023;
    Gcat[(size_t)384 * 1024 + idx] = f2bf(X_t[dd * 64 + (r & 63)]);
  } else if (bx < 12544) {                // WO -> bf16
    int i = (bx - 11520) * 256 + tid;
    float4 v = ((const float4*)WO)[i];
    ushort4 o; o.x = f2bf(v.x); o.y = f2bf(v.y); o.z = f2bf(v.z); o.w = f2bf(v.w);
    ((ushort4*)WOb)[i] = o;
  } else {                                // obias[n]
    int n = bx - 12544;
    const float abi = abi_p[0], atri = atri_p[0];
    float s = 0.f;
    for (int d0 = tid; d0 < 1024; d0 += 256)
      s += ((1.f + abi) * bias_b[d0] + atri * bias_t[d0]) * WO[(size_t)n * 1024 + d0];
    smem[tid] = s;
    __syncthreads();
#pragma unroll
    for (int w = 128; w > 0; w >>= 1) {
      if (tid < w) smem[tid] += smem[tid + w];
      __syncthreads();
    }
    if (tid == 0) obias[n] = smem[0];
  }
}

// ---------------------------------------------------------------------------
// scanC: parallel exclusive prefix over the 128 chunk sums (both splits added)
// per (b, col). One wave per (b,col); lanes = chunk pairs; shfl_up scan.
// ---------------------------------------------------------------------------
__global__ __launch_bounds__(256) void scanC_k(const float* __restrict__ sums,
                                               float* __restrict__ carry)
{
  const int W = blockIdx.x * 4 + (threadIdx.x >> 6);   // 0..1023
  const int lane = threadIdx.x & 63;
  const int b = W >> 8, col = W & 255;
  const int ch0 = lane << 1;
  const size_t i0 = ((((size_t)b << 7) + ch0) << 8) + col;
  const size_t i1 = i0 + 256;
  const float v0 = sums[i0] + sums[i0 + 131072];
  const float v1 = sums[i1] + sums[i1 + 131072];
  float a = v0 + v1;
#pragma unroll
  for (int off = 1; off < 64; off <<= 1) {
    const float u = __shfl_up(a, off);
    if (lane >= off) a += u;
  }
  const float excl = a - (v0 + v1);   // exclusive prefix for chunk ch0
  carry[i0] = excl;
  carry[i1] = excl + v0;
}

// ---------------------------------------------------------------------------
// scanB: 16-row chunks, carry preloaded from scanC, combine -> rcat bf16.
// Pcat cols: 0:p1 64:p5 128:s2 192:s6 256:s3 320:p4 384:sZ (per split)
// ---------------------------------------------------------------------------
__global__ __launch_bounds__(256) void scanB_k(
    const unsigned short* __restrict__ P, const float* __restrict__ carry,
    const float* __restrict__ abi_p, const float* __restrict__ atri_p,
    unsigned short* __restrict__ rcat)
{
  const int w = blockIdx.x * 4 + (threadIdx.x >> 6);   // 0..511
  const int lane = threadIdx.x & 63;
  const int b = w >> 7, ch = w & 127;
  const float* cp = carry + ((((size_t)b << 7) + ch) << 8) + lane;
  float c2 = cp[0], c6 = cp[64], c3 = cp[128], cZ = cp[192];
  const float abi = abi_p[0], atri = atri_p[0];
  const size_t row0 = (size_t)b * T_LEN + ch * 16;
  const unsigned short* P1 = P + (size_t)BT_DIM * 512;
#pragma unroll 4
  for (int t = 0; t < 16; ++t) {
    const size_t ro = (row0 + t) * 512 + lane;
    const float p1 = bf2f(P[ro])       + bf2f(P1[ro]);
    const float p5 = bf2f(P[ro + 64])  + bf2f(P1[ro + 64]);
    c2            += bf2f(P[ro + 128]) + bf2f(P1[ro + 128]);
    c6            += bf2f(P[ro + 192]) + bf2f(P1[ro + 192]);
    c3            += bf2f(P[ro + 256]) + bf2f(P1[ro + 256]);
    const float p4 = bf2f(P[ro + 320]) + bf2f(P1[ro + 320]);
    cZ            += bf2f(P[ro + 384]) + bf2f(P1[ro + 384]);
    const float invc = 1.0f / (float)(ch * 16 + t + 1);
    const float rb = (p1 * c2 + abi * (c3 * p4)) * invc;
    const float rt = atri * p5 * c6 * cZ * invc * invc;
    const size_t rro = (row0 + t) * 128;
    rcat[rro + lane]      = f2bf(rb);
    rcat[rro + 64 + lane] = f2bf(rt);
  }
}

// ---------------------------------------------------------------------------
extern "C" void kernel_launch(void* const* d_in, const int* in_sizes, int n_in,
                              void* d_out, int out_size, void* d_ws, size_t ws_size,
                              hipStream_t stream)
{
  const float* x      = (const float*)d_in[0];
  const float* WQ     = (const float*)d_in[1];
  const float* WK     = (const float*)d_in[2];
  const float* WO     = (const float*)d_in[3];
  const float* Winv   = (const float*)d_in[4];
  const float* U_b    = (const float*)d_in[5];
  const float* V_b    = (const float*)d_in[6];
  const float* W_b    = (const float*)d_in[7];
  const float* bias_b = (const float*)d_in[8];
  const float* U_t    = (const float*)d_in[9];
  const float* V_t    = (const float*)d_in[10];
  const float* W_t    = (const float*)d_in[11];
  const float* X_t    = (const float*)d_in[12];
  const float* bias_t = (const float*)d_in[13];
  const float* a_bi   = (const float*)d_in[14];
  const float* a_tri  = (const float*)d_in[15];

  char* ws = (char*)d_ws;
  size_t off = 0;
  unsigned short* xb    = (unsigned short*)(ws + off); off += (size_t)BT_DIM * 1024 * 2;     // 16MB
  unsigned short* Pcat  = (unsigned short*)(ws + off); off += (size_t)2 * BT_DIM * 512 * 2;  // 16MB (2 splits)
  unsigned short* rcat  = (unsigned short*)(ws + off); off += (size_t)BT_DIM * 128 * 2;      // 2MB
  unsigned short* WQt   = (unsigned short*)(ws + off); off += 2097152;
  unsigned short* WKt   = (unsigned short*)(ws + off); off += 2097152;
  unsigned short* Winvt = (unsigned short*)(ws + off); off += 2097152;
  unsigned short* WOb   = (unsigned short*)(ws + off); off += 2097152;
  unsigned short* BQ    = (unsigned short*)(ws + off); off += 262144;
  unsigned short* BK    = (unsigned short*)(ws + off); off += 262144;
  unsigned short* BI    = (unsigned short*)(ws + off); off += 262144;
  unsigned short* Hb    = (unsigned short*)(ws + off); off += 262144;
  unsigned short* UcatT = (unsigned short*)(ws + off); off += 262144;
  unsigned short* Gcat  = (unsigned short*)(ws + off); off += (size_t)512 * 1024 * 2;        // 1MB
  unsigned short* Gfin  = (unsigned short*)(ws + off); off += 262144;
  float*          obias = (float*)(ws + off);          off += 4096;
  float*          sums  = (float*)(ws + off);          off += 1048576;  // 2 splits * 512 chunks * 256 f32
  float*          carry = (float*)(ws + off);          off += 524288;   // 4b * 128ch * 256 f32

  prep_k<<<dim3(13568), 256, 0, stream>>>(x, WQ, WK, WO, Winv, U_b, V_b, W_b, bias_b,
                                          U_t, V_t, W_t, X_t, bias_t, a_bi, a_tri,
                                          xb, WQt, WKt, Winvt, WOb, BQ, BK, BI,
                                          UcatT, Gcat, obias);
  smallA_k<<<dim3(8, 4), 256, 0, stream>>>(BQ, BK, BI, WOb, WQt, WKt, Winvt, UcatT,
                                           Gcat, Hb, Gfin);
  smallB_k<<<dim3(8, 2), 256, 0, stream>>>(Hb, WKt, WQt, Gcat);
  mainP_k<<<dim3(64, 4, 2), 256, 0, stream>>>(xb, Gcat, Pcat, sums);
  scanC_k<<<dim3(256), 256, 0, stream>>>(sums, carry);
  scanB_k<<<dim3(128), 256, 0, stream>>>(Pcat, carry, a_bi, a_tri, rcat);
  final_k<<<dim3(64, 8), 256, 0, stream>>>(rcat, Gfin, obias, (float*)d_out);
}